// Round 13
// baseline (289.575 us; speedup 1.0000x reference)
//
#include <hip/hip_runtime.h>

#define NQ    10
#define NPRM  100
#define NBATCH 8192

using F2 = __attribute__((ext_vector_type(2))) float;

__device__ __forceinline__ F2 mk2(float a, float b) { F2 v; v.x = a; v.y = b; return v; }

// ---------------- cross-lane XOR exchange ----------------
// masks 1,2,8: DPP on VALU pipe; 4,16,32: ds_swizzle via __shfl_xor (R7-verified)

template<int LM>
__device__ __forceinline__ float lshf(float v) {
  if constexpr (LM == 1) {
    int r = __builtin_amdgcn_update_dpp(0, __builtin_bit_cast(int, v), 0xB1, 0xF, 0xF, true);
    return __builtin_bit_cast(float, r);
  } else if constexpr (LM == 2) {
    int r = __builtin_amdgcn_update_dpp(0, __builtin_bit_cast(int, v), 0x4E, 0xF, 0xF, true);
    return __builtin_bit_cast(float, r);
  } else if constexpr (LM == 8) {
    int r = __builtin_amdgcn_update_dpp(0, __builtin_bit_cast(int, v), 0x128, 0xF, 0xF, true);
    return __builtin_bit_cast(float, r);
  } else {
    return __shfl_xor(v, LM, 64);
  }
}
template<int LM>
__device__ __forceinline__ F2 lshf2(F2 v) {
  return mk2(lshf<LM>(v.x), lshf<LM>(v.y));
}

// Amplitude index i (10 bits): bits 0..3 = per-lane register index r, bits 4..9 = lane id.
// Wire w corresponds to global bit P = 9 - w (wire 0 = MSB, PennyLane order).

// ================= PACKED gate set: F2 lo half = elem b0, hi half = elem b1 =================
// All operations element-wise on F2 (R9/R12-verified primitives, unchanged).

struct UU { F2 x00, y00, x01, y01; };

template<int P>
__device__ __forceinline__ void g_u2(F2* sR, F2* sI, unsigned lane, UU u) {
  if constexpr (P < 4) {
    constexpr int m = 1 << P;
#pragma unroll
    for (int r = 0; r < 16; ++r) if (!(r & m)) {
      const int r1 = r | m;
      F2 R0 = sR[r], I0 = sI[r], R1 = sR[r1], I1 = sI[r1];
      sR[r]  = u.x00*R0 - u.y00*I0 + u.x01*R1 - u.y01*I1;
      sI[r]  = u.x00*I0 + u.y00*R0 + u.x01*I1 + u.y01*R1;
      sR[r1] = u.x00*R1 + u.y00*I1 - u.x01*R0 - u.y01*I0;
      sI[r1] = u.x00*I1 - u.y00*R1 - u.x01*I0 + u.y01*R0;
    }
  } else {
    constexpr int lm = 1 << (P - 4);
    const bool hi = (lane & lm) != 0;
    const F2 vay = mk2(hi ? -u.y00.x : u.y00.x, hi ? -u.y00.y : u.y00.y);
    const F2 vbx = mk2(hi ? -u.x01.x : u.x01.x, hi ? -u.x01.y : u.x01.y);
#pragma unroll
    for (int r = 0; r < 16; ++r) {
      F2 R = sR[r], I = sI[r];
      F2 oR = lshf2<lm>(R), oI = lshf2<lm>(I);
      sR[r] = u.x00*R - vay*I + vbx*oR - u.y01*oI;
      sI[r] = u.x00*I + vay*R + vbx*oI + u.y01*oR;
    }
  }
}

template<int P>
__device__ __forceinline__ void g_rx2(F2* sR, F2* sI, unsigned lane, F2 C, F2 S) {
  if constexpr (P < 4) {
    constexpr int m = 1 << P;
#pragma unroll
    for (int r = 0; r < 16; ++r) if (!(r & m)) {
      const int r1 = r | m;
      F2 R0 = sR[r], I0 = sI[r], R1 = sR[r1], I1 = sI[r1];
      sR[r]  = C*R0 + S*I1;
      sI[r]  = C*I0 - S*R1;
      sR[r1] = C*R1 + S*I0;
      sI[r1] = C*I1 - S*R0;
    }
  } else {
    constexpr int lm = 1 << (P - 4);
#pragma unroll
    for (int r = 0; r < 16; ++r) {
      F2 R = sR[r], I = sI[r];
      F2 oR = lshf2<lm>(R), oI = lshf2<lm>(I);
      sR[r] = C*R + S*oI;
      sI[r] = C*I - S*oR;
    }
  }
}

template<int TB, int CB>
__device__ __forceinline__ void g_crx2(F2* sR, F2* sI, unsigned lane, F2 C, F2 S) {
  if constexpr (CB >= 4) {
    const bool act = (lane >> (CB - 4)) & 1u;
    const F2 Ce = mk2(act ? C.x : 1.0f, act ? C.y : 1.0f);
    const F2 Se = mk2(act ? S.x : 0.0f, act ? S.y : 0.0f);
    g_rx2<TB>(sR, sI, lane, Ce, Se);
  } else {
    constexpr int cm = 1 << CB;
    if constexpr (TB < 4) {
#pragma unroll
      for (int r = 0; r < 16; ++r) if ((r & cm) && !(r & (1 << TB))) {
        const int r1 = r | (1 << TB);
        F2 R0 = sR[r], I0 = sI[r], R1 = sR[r1], I1 = sI[r1];
        sR[r]  = C*R0 + S*I1;
        sI[r]  = C*I0 - S*R1;
        sR[r1] = C*R1 + S*I0;
        sI[r1] = C*I1 - S*R0;
      }
    } else {
      constexpr int lm = 1 << (TB - 4);
#pragma unroll
      for (int r = 0; r < 16; ++r) if (r & cm) {
        F2 R = sR[r], I = sI[r];
        F2 oR = lshf2<lm>(R), oI = lshf2<lm>(I);
        sR[r] = C*R + S*oI;
        sI[r] = C*I - S*oR;
      }
    }
  }
}

__device__ __forceinline__ void g_u2_w(F2* sR, F2* sI, unsigned lane, int w, UU u) {
  switch (w) {
    case 0: g_u2<9>(sR,sI,lane,u); break;
    case 1: g_u2<8>(sR,sI,lane,u); break;
    case 2: g_u2<7>(sR,sI,lane,u); break;
    case 3: g_u2<6>(sR,sI,lane,u); break;
    case 4: g_u2<5>(sR,sI,lane,u); break;
    case 5: g_u2<4>(sR,sI,lane,u); break;
    case 6: g_u2<3>(sR,sI,lane,u); break;
    case 7: g_u2<2>(sR,sI,lane,u); break;
    case 8: g_u2<1>(sR,sI,lane,u); break;
    case 9: g_u2<0>(sR,sI,lane,u); break;
  }
}

#define CRX2_CASE(CW,TW) case (CW)*10+(TW): g_crx2<9-(TW), 9-(CW)>(sR,sI,lane,C,S); break;
__device__ __forceinline__ void crx2_w(F2* sR, F2* sI, unsigned lane, int cw, int tw, F2 C, F2 S) {
  switch (cw * 10 + tw) {
    CRX2_CASE(0,1) CRX2_CASE(1,2) CRX2_CASE(2,3) CRX2_CASE(3,4) CRX2_CASE(4,5)
    CRX2_CASE(5,6) CRX2_CASE(6,7) CRX2_CASE(7,8) CRX2_CASE(8,9) CRX2_CASE(9,0)
    CRX2_CASE(1,0) CRX2_CASE(2,1) CRX2_CASE(3,2) CRX2_CASE(4,3) CRX2_CASE(5,4)
    CRX2_CASE(6,5) CRX2_CASE(7,6) CRX2_CASE(8,7) CRX2_CASE(9,8) CRX2_CASE(0,9)
  }
}

// U = RZ(az)*RY(ay)*RX(ax); SU(2): only u00,u01 needed (scalar, one elem)
__device__ __forceinline__ void make_u(float ax, float ay, float az, F2& u00, F2& u01) {
  float ca, sa, cb, sb, cg, sg;
  __sincosf(ax*0.5f, &sa, &ca);
  __sincosf(ay*0.5f, &sb, &cb);
  __sincosf(az*0.5f, &sg, &cg);
  const float m00x =  cb*ca, m00y =  sb*sa;
  const float m01x = -sb*ca, m01y = -cb*sa;
  u00 = mk2(m00x*cg + m00y*sg, m00y*cg - m00x*sg);
  u01 = mk2(m01x*cg + m01y*sg, m01y*cg - m01x*sg);
}

__device__ __forceinline__ UU pack_u(const float* P0, const float* P1, float dt0, float dt1, int off) {
  F2 u00a, u01a, u00b, u01b;
  make_u(P0[off]*dt0, P0[off+1]*dt0, P0[off+2]*dt0, u00a, u01a);
  make_u(P1[off]*dt1, P1[off+1]*dt1, P1[off+2]*dt1, u00b, u01b);
  UU u;
  u.x00 = mk2(u00a.x, u00b.x); u.y00 = mk2(u00a.y, u00b.y);
  u.x01 = mk2(u01a.x, u01b.x); u.y01 = mk2(u01a.y, u01b.y);
  return u;
}

__device__ __forceinline__ void pack_cs(const float* P0, const float* P1, int off, F2& C, F2& S) {
  float s0, c0, s1, c1;
  __sincosf(P0[off]*0.5f, &s0, &c0);
  __sincosf(P1[off]*0.5f, &s1, &c1);
  C = mk2(c0, c1); S = mk2(s0, s1);
}

// forward-order layer (fwd: dt=dts; diag: dt=1)
__device__ __forceinline__ void layer_fwd2(F2* sR, F2* sI, unsigned lane,
                                           const float* P0, const float* P1,
                                           float dt0, float dt1, int& off) {
#pragma unroll
  for (int i = 0; i < NQ; ++i) {
    g_u2_w(sR, sI, lane, i, pack_u(P0, P1, dt0, dt1, off));
    off += 3;
  }
#pragma unroll
  for (int i = 0; i < NQ; ++i) {
    F2 C, S; pack_cs(P0, P1, off, C, S);
    crx2_w(sR, sI, lane, i, (i+1)%NQ, C, S); ++off;
  }
#pragma unroll
  for (int i = NQ-1; i >= 0; --i) {
    F2 C, S; pack_cs(P0, P1, off, C, S);
    crx2_w(sR, sI, lane, i, (i+NQ-1)%NQ, C, S); ++off;
  }
}

// backward-order layer (mechanical transform of R7-verified layer_bwd)
__device__ __forceinline__ void layer_bwd2(F2* sR, F2* sI, unsigned lane,
                                           const float* P0, const float* P1,
                                           float dt0, float dt1, int& off) {
#pragma unroll
  for (int i = NQ-1; i >= 0; --i) {
    g_u2_w(sR, sI, lane, i, pack_u(P0, P1, dt0, dt1, off));
    off += 3;
  }
#pragma unroll
  for (int i = NQ-1; i >= 0; --i) {
    F2 C, S; pack_cs(P0, P1, off, C, S);
    crx2_w(sR, sI, lane, i, (i+NQ-1)%NQ, C, S); ++off;
  }
#pragma unroll
  for (int i = 0; i < NQ; ++i) {
    F2 C, S; pack_cs(P0, P1, off, C, S);
    crx2_w(sR, sI, lane, i, (i+1)%NQ, C, S); ++off;
  }
}

// RY-embedded |0..0> product state, both elems in F2 halves
__device__ __forceinline__ void init_state2e(F2* sR, F2* sI, unsigned lane,
                                             const float* ang0, const float* ang1) {
  float cw0[NQ], sw0[NQ], cw1[NQ], sw1[NQ];
#pragma unroll
  for (int w = 0; w < NQ; ++w) {
    __sincosf(ang0[w]*0.5f, &sw0[w], &cw0[w]);
    __sincosf(ang1[w]*0.5f, &sw1[w], &cw1[w]);
  }
  F2 L = mk2(1.0f, 1.0f);
#pragma unroll
  for (int q = 0; q < 6; ++q) {          // lane bit q <-> wire 5-q
    const int w = 5-q;
    L *= ((lane >> q) & 1u) ? mk2(sw0[w], sw1[w]) : mk2(cw0[w], cw1[w]);
  }
#pragma unroll
  for (int r = 0; r < 16; ++r) {
    F2 R = L;
#pragma unroll
    for (int p = 0; p < 4; ++p) {        // reg bit p <-> wire 9-p
      const int w = 9-p;
      R *= ((r >> p) & 1) ? mk2(sw0[w], sw1[w]) : mk2(cw0[w], cw1[w]);
    }
    sR[r] = R;
    sI[r] = mk2(0.0f, 0.0f);
  }
}

// ---------------- packed measurement (both elems at once) ----------------

template<int P>
__device__ __forceinline__ void meas2(const F2* sRe, const F2* sIm, unsigned lane,
                                      F2& X, F2& Y, F2& Z) {
  F2 cr = mk2(0,0), ci = mk2(0,0), z = mk2(0,0);
  if constexpr (P < 4) {
    constexpr int m = 1 << P;
#pragma unroll
    for (int r = 0; r < 16; ++r) if (!(r & m)) {
      const int r1 = r | m;
      F2 aR = sRe[r], aI = sIm[r], bR = sRe[r1], bI = sIm[r1];
      cr += aR*bR + aI*bI;
      ci += aR*bI - aI*bR;
      z  += (aR*aR + aI*aI) - (bR*bR + bI*bI);
    }
    cr = cr + cr; ci = ci + ci;          // *2
  } else {
    constexpr int lm = 1 << (P - 4);
    const bool hi = (lane & lm) != 0;
#pragma unroll
    for (int r = 0; r < 16; ++r) {
      F2 mR = sRe[r], mI = sIm[r];
      F2 oR = lshf2<lm>(mR), oI = lshf2<lm>(mI);
      F2 a0R = hi ? oR : mR, a0I = hi ? oI : mI;
      F2 a1R = hi ? mR : oR, a1I = hi ? mI : oI;
      cr += a0R*a1R + a0I*a1I;           // pair counted twice across lanes -> no *2
      ci += a0R*a1I - a0I*a1R;
      F2 p2 = mR*mR + mI*mI;
      z += hi ? -p2 : p2;
    }
  }
  X = cr; Y = ci; Z = z;
}

__device__ __forceinline__ F2 wred2(F2 v) {
  v += lshf2<1>(v);
  v += lshf2<2>(v);
  v += lshf2<4>(v);
  v += lshf2<8>(v);
  v += lshf2<16>(v);
  v += lshf2<32>(v);
  return v;
}

// ---------------- kernel: 1 block = 3 waves = 2 batch elems; one packed circuit per wave ----------------
// wave0=fwd, wave1=bwd, wave2=diag; each simulates BOTH elems (F2 halves).
// Waves 1,2 write weighted states to LDS and exit; wave0 combines + norms + packed-measures.
// No accumulator co-resident with a live circuit state -> live set ~80 regs.

__global__ void __launch_bounds__(192, 2) qsim_kernel(
    const float* __restrict__ angles, const float* __restrict__ fwdP,
    const float* __restrict__ bwdP,   const float* __restrict__ diagP,
    const float* __restrict__ dts,
    const float* __restrict__ ar, const float* __restrict__ ai,
    const float* __restrict__ br, const float* __restrict__ bi,
    const float* __restrict__ gr, const float* __restrict__ gi,
    float* __restrict__ out)
{
  __shared__ F2 ldsR[2][16][64];   // weighted states of waves 1 (bwd), 2 (diag)
  __shared__ F2 ldsI[2][16][64];   // 32 KB total

  const int wave = threadIdx.x >> 6;
  const unsigned lane = threadIdx.x & 63u;
  const int b0 = blockIdx.x * 2;
  const int b1 = b0 + 1;

  const float* ang0 = angles + b0 * NQ;
  const float* ang1 = angles + b1 * NQ;
  const float dt0 = dts[b0], dt1 = dts[b1];

  const float arv = ar[0], aiv = ai[0], brv = br[0], biv = bi[0], grv = gr[0], giv = gi[0];
  const float nrm = sqrtf(arv*arv + aiv*aiv + brv*brv + biv*biv + grv*grv + giv*giv + 1e-9f);
  const float cAx = arv/nrm, cAy = aiv/nrm;
  const float cBx = brv/nrm, cBy = biv/nrm;
  const float cGx = grv/nrm, cGy = giv/nrm;

  F2 sR[16], sI[16];
  init_state2e(sR, sI, lane, ang0, ang1);

  if (wave == 0) {
    int off = 0;
    const float* P0 = fwdP + b0*NPRM;
    const float* P1 = fwdP + b1*NPRM;
#pragma unroll
    for (int l = 0; l < 2; ++l) layer_fwd2(sR, sI, lane, P0, P1, dt0, dt1, off);
  } else if (wave == 1) {
    int off = 0;
    const float* P0 = bwdP + b0*NPRM;
    const float* P1 = bwdP + b1*NPRM;
#pragma unroll
    for (int l = 0; l < 2; ++l) layer_bwd2(sR, sI, lane, P0, P1, dt0, dt1, off);
  } else {
    int off = 0;
    const float* P0 = diagP + b0*NPRM;
    const float* P1 = diagP + b1*NPRM;
#pragma unroll
    for (int l = 0; l < 2; ++l) layer_fwd2(sR, sI, lane, P0, P1, 1.0f, 1.0f, off);
  }

  if (wave != 0) {
    const float wx = (wave == 1) ? cBx : cGx;
    const float wy = (wave == 1) ? cBy : cGy;
#pragma unroll
    for (int r = 0; r < 16; ++r) {
      ldsR[wave-1][r][lane] = wx*sR[r] - wy*sI[r];
      ldsI[wave-1][r][lane] = wx*sI[r] + wy*sR[r];
    }
  }
  __syncthreads();
  if (wave != 0) return;

  // wave0: combine (cA * own fwd state + LDS states), normalize, measure
#pragma unroll
  for (int r = 0; r < 16; ++r) {
    F2 nR = cAx*sR[r] - cAy*sI[r] + ldsR[0][r][lane] + ldsR[1][r][lane];
    F2 nI = cAx*sI[r] + cAy*sR[r] + ldsI[0][r][lane] + ldsI[1][r][lane];
    sR[r] = nR; sI[r] = nI;
  }

  F2 n2 = mk2(0.0f, 0.0f);
#pragma unroll
  for (int r = 0; r < 16; ++r) n2 += sR[r]*sR[r] + sI[r]*sI[r];
  n2 = wred2(n2);
  const F2 inv = mk2(1.0f/(sqrtf(n2.x)+1e-9f), 1.0f/(sqrtf(n2.y)+1e-9f));
#pragma unroll
  for (int r = 0; r < 16; ++r) { sR[r] *= inv; sI[r] *= inv; }

  float* o0 = out + b0 * 30;
  float* o1 = out + b1 * 30;
#pragma unroll
  for (int w = 0; w < NQ; ++w) {
    F2 X, Y, Z;
    switch (w) {
      case 0: meas2<9>(sR, sI, lane, X, Y, Z); break;
      case 1: meas2<8>(sR, sI, lane, X, Y, Z); break;
      case 2: meas2<7>(sR, sI, lane, X, Y, Z); break;
      case 3: meas2<6>(sR, sI, lane, X, Y, Z); break;
      case 4: meas2<5>(sR, sI, lane, X, Y, Z); break;
      case 5: meas2<4>(sR, sI, lane, X, Y, Z); break;
      case 6: meas2<3>(sR, sI, lane, X, Y, Z); break;
      case 7: meas2<2>(sR, sI, lane, X, Y, Z); break;
      case 8: meas2<1>(sR, sI, lane, X, Y, Z); break;
      default: meas2<0>(sR, sI, lane, X, Y, Z); break;
    }
    X = wred2(X); Y = wred2(Y); Z = wred2(Z);
    if (lane == 0) {
      o0[w] = X.x; o0[10 + w] = Y.x; o0[20 + w] = Z.x;
      o1[w] = X.y; o1[10 + w] = Y.y; o1[20 + w] = Z.y;
    }
  }
}

extern "C" void kernel_launch(void* const* d_in, const int* in_sizes, int n_in,
                              void* d_out, int out_size, void* d_ws, size_t ws_size,
                              hipStream_t stream) {
  const float* angles = (const float*)d_in[0];
  const float* fwdP   = (const float*)d_in[1];
  const float* bwdP   = (const float*)d_in[2];
  const float* diagP  = (const float*)d_in[3];
  const float* dts    = (const float*)d_in[4];
  const float* ar     = (const float*)d_in[5];
  const float* ai     = (const float*)d_in[6];
  const float* br     = (const float*)d_in[7];
  const float* bi     = (const float*)d_in[8];
  const float* gr     = (const float*)d_in[9];
  const float* gi     = (const float*)d_in[10];
  float* out = (float*)d_out;

  // one block per 2 batch elements; 3 waves = {fwd, bwd, diag}, each packed over both elems
  qsim_kernel<<<NBATCH/2, 192, 0, stream>>>(
      angles, fwdP, bwdP, diagP, dts, ar, ai, br, bi, gr, gi, out);
}

// Round 14
// 285.806 us; speedup vs baseline: 1.0132x; 1.0132x over previous
//
#include <hip/hip_runtime.h>

#define NQ    10
#define NPRM  100
#define NBATCH 8192

using F2 = __attribute__((ext_vector_type(2))) float;

__device__ __forceinline__ F2 mk2(float a, float b) { F2 v; v.x = a; v.y = b; return v; }

// ---------------- cross-lane XOR exchange ----------------
// masks 1,2,8: DPP on VALU pipe; 4,16,32: ds_swizzle via __shfl_xor (R7-verified)

template<int LM>
__device__ __forceinline__ float lshf(float v) {
  if constexpr (LM == 1) {
    int r = __builtin_amdgcn_update_dpp(0, __builtin_bit_cast(int, v), 0xB1, 0xF, 0xF, true);
    return __builtin_bit_cast(float, r);
  } else if constexpr (LM == 2) {
    int r = __builtin_amdgcn_update_dpp(0, __builtin_bit_cast(int, v), 0x4E, 0xF, 0xF, true);
    return __builtin_bit_cast(float, r);
  } else if constexpr (LM == 8) {
    int r = __builtin_amdgcn_update_dpp(0, __builtin_bit_cast(int, v), 0x128, 0xF, 0xF, true);
    return __builtin_bit_cast(float, r);
  } else {
    return __shfl_xor(v, LM, 64);
  }
}
template<int LM>
__device__ __forceinline__ F2 lshf2(F2 v) {
  return mk2(lshf<LM>(v.x), lshf<LM>(v.y));
}

// Amplitude index i (10 bits): bits 0..3 = per-lane register index r, bits 4..9 = lane id.
// Wire w corresponds to global bit P = 9 - w (wire 0 = MSB, PennyLane order).

// ================= PACKED gate set: F2 lo half = elem b0, hi half = elem b1 =================
// All operations element-wise on F2 (R9/R12/R13-verified primitives, unchanged).

struct UU { F2 x00, y00, x01, y01; };

template<int P>
__device__ __forceinline__ void g_u2(F2* sR, F2* sI, unsigned lane, UU u) {
  if constexpr (P < 4) {
    constexpr int m = 1 << P;
#pragma unroll
    for (int r = 0; r < 16; ++r) if (!(r & m)) {
      const int r1 = r | m;
      F2 R0 = sR[r], I0 = sI[r], R1 = sR[r1], I1 = sI[r1];
      sR[r]  = u.x00*R0 - u.y00*I0 + u.x01*R1 - u.y01*I1;
      sI[r]  = u.x00*I0 + u.y00*R0 + u.x01*I1 + u.y01*R1;
      sR[r1] = u.x00*R1 + u.y00*I1 - u.x01*R0 - u.y01*I0;
      sI[r1] = u.x00*I1 - u.y00*R1 - u.x01*I0 + u.y01*R0;
    }
  } else {
    constexpr int lm = 1 << (P - 4);
    const bool hi = (lane & lm) != 0;
    const F2 vay = mk2(hi ? -u.y00.x : u.y00.x, hi ? -u.y00.y : u.y00.y);
    const F2 vbx = mk2(hi ? -u.x01.x : u.x01.x, hi ? -u.x01.y : u.x01.y);
#pragma unroll
    for (int r = 0; r < 16; ++r) {
      F2 R = sR[r], I = sI[r];
      F2 oR = lshf2<lm>(R), oI = lshf2<lm>(I);
      sR[r] = u.x00*R - vay*I + vbx*oR - u.y01*oI;
      sI[r] = u.x00*I + vay*R + vbx*oI + u.y01*oR;
    }
  }
}

template<int P>
__device__ __forceinline__ void g_rx2(F2* sR, F2* sI, unsigned lane, F2 C, F2 S) {
  if constexpr (P < 4) {
    constexpr int m = 1 << P;
#pragma unroll
    for (int r = 0; r < 16; ++r) if (!(r & m)) {
      const int r1 = r | m;
      F2 R0 = sR[r], I0 = sI[r], R1 = sR[r1], I1 = sI[r1];
      sR[r]  = C*R0 + S*I1;
      sI[r]  = C*I0 - S*R1;
      sR[r1] = C*R1 + S*I0;
      sI[r1] = C*I1 - S*R0;
    }
  } else {
    constexpr int lm = 1 << (P - 4);
#pragma unroll
    for (int r = 0; r < 16; ++r) {
      F2 R = sR[r], I = sI[r];
      F2 oR = lshf2<lm>(R), oI = lshf2<lm>(I);
      sR[r] = C*R + S*oI;
      sI[r] = C*I - S*oR;
    }
  }
}

template<int TB, int CB>
__device__ __forceinline__ void g_crx2(F2* sR, F2* sI, unsigned lane, F2 C, F2 S) {
  if constexpr (CB >= 4) {
    const bool act = (lane >> (CB - 4)) & 1u;
    const F2 Ce = mk2(act ? C.x : 1.0f, act ? C.y : 1.0f);
    const F2 Se = mk2(act ? S.x : 0.0f, act ? S.y : 0.0f);
    g_rx2<TB>(sR, sI, lane, Ce, Se);
  } else {
    constexpr int cm = 1 << CB;
    if constexpr (TB < 4) {
#pragma unroll
      for (int r = 0; r < 16; ++r) if ((r & cm) && !(r & (1 << TB))) {
        const int r1 = r | (1 << TB);
        F2 R0 = sR[r], I0 = sI[r], R1 = sR[r1], I1 = sI[r1];
        sR[r]  = C*R0 + S*I1;
        sI[r]  = C*I0 - S*R1;
        sR[r1] = C*R1 + S*I0;
        sI[r1] = C*I1 - S*R0;
      }
    } else {
      constexpr int lm = 1 << (TB - 4);
#pragma unroll
      for (int r = 0; r < 16; ++r) if (r & cm) {
        F2 R = sR[r], I = sI[r];
        F2 oR = lshf2<lm>(R), oI = lshf2<lm>(I);
        sR[r] = C*R + S*oI;
        sI[r] = C*I - S*oR;
      }
    }
  }
}

__device__ __forceinline__ void g_u2_w(F2* sR, F2* sI, unsigned lane, int w, UU u) {
  switch (w) {
    case 0: g_u2<9>(sR,sI,lane,u); break;
    case 1: g_u2<8>(sR,sI,lane,u); break;
    case 2: g_u2<7>(sR,sI,lane,u); break;
    case 3: g_u2<6>(sR,sI,lane,u); break;
    case 4: g_u2<5>(sR,sI,lane,u); break;
    case 5: g_u2<4>(sR,sI,lane,u); break;
    case 6: g_u2<3>(sR,sI,lane,u); break;
    case 7: g_u2<2>(sR,sI,lane,u); break;
    case 8: g_u2<1>(sR,sI,lane,u); break;
    case 9: g_u2<0>(sR,sI,lane,u); break;
  }
}

#define CRX2_CASE(CW,TW) case (CW)*10+(TW): g_crx2<9-(TW), 9-(CW)>(sR,sI,lane,C,S); break;
__device__ __forceinline__ void crx2_w(F2* sR, F2* sI, unsigned lane, int cw, int tw, F2 C, F2 S) {
  switch (cw * 10 + tw) {
    CRX2_CASE(0,1) CRX2_CASE(1,2) CRX2_CASE(2,3) CRX2_CASE(3,4) CRX2_CASE(4,5)
    CRX2_CASE(5,6) CRX2_CASE(6,7) CRX2_CASE(7,8) CRX2_CASE(8,9) CRX2_CASE(9,0)
    CRX2_CASE(1,0) CRX2_CASE(2,1) CRX2_CASE(3,2) CRX2_CASE(4,3) CRX2_CASE(5,4)
    CRX2_CASE(6,5) CRX2_CASE(7,6) CRX2_CASE(8,7) CRX2_CASE(9,8) CRX2_CASE(0,9)
  }
}

// U = RZ(az)*RY(ay)*RX(ax); SU(2): only u00,u01 needed (scalar, one elem)
__device__ __forceinline__ void make_u(float ax, float ay, float az, F2& u00, F2& u01) {
  float ca, sa, cb, sb, cg, sg;
  __sincosf(ax*0.5f, &sa, &ca);
  __sincosf(ay*0.5f, &sb, &cb);
  __sincosf(az*0.5f, &sg, &cg);
  const float m00x =  cb*ca, m00y =  sb*sa;
  const float m01x = -sb*ca, m01y = -cb*sa;
  u00 = mk2(m00x*cg + m00y*sg, m00y*cg - m00x*sg);
  u01 = mk2(m01x*cg + m01y*sg, m01y*cg - m01x*sg);
}

__device__ __forceinline__ UU pack_u(const float* P0, const float* P1, float dt0, float dt1, int off) {
  F2 u00a, u01a, u00b, u01b;
  make_u(P0[off]*dt0, P0[off+1]*dt0, P0[off+2]*dt0, u00a, u01a);
  make_u(P1[off]*dt1, P1[off+1]*dt1, P1[off+2]*dt1, u00b, u01b);
  UU u;
  u.x00 = mk2(u00a.x, u00b.x); u.y00 = mk2(u00a.y, u00b.y);
  u.x01 = mk2(u01a.x, u01b.x); u.y01 = mk2(u01a.y, u01b.y);
  return u;
}

__device__ __forceinline__ void pack_cs(const float* P0, const float* P1, int off, F2& C, F2& S) {
  float s0, c0, s1, c1;
  __sincosf(P0[off]*0.5f, &s0, &c0);
  __sincosf(P1[off]*0.5f, &s1, &c1);
  C = mk2(c0, c1); S = mk2(s0, s1);
}

// forward-order layer (fwd: dt=dts; diag: dt=1)
__device__ __forceinline__ void layer_fwd2(F2* sR, F2* sI, unsigned lane,
                                           const float* P0, const float* P1,
                                           float dt0, float dt1, int& off) {
#pragma unroll
  for (int i = 0; i < NQ; ++i) {
    g_u2_w(sR, sI, lane, i, pack_u(P0, P1, dt0, dt1, off));
    off += 3;
  }
#pragma unroll
  for (int i = 0; i < NQ; ++i) {
    F2 C, S; pack_cs(P0, P1, off, C, S);
    crx2_w(sR, sI, lane, i, (i+1)%NQ, C, S); ++off;
  }
#pragma unroll
  for (int i = NQ-1; i >= 0; --i) {
    F2 C, S; pack_cs(P0, P1, off, C, S);
    crx2_w(sR, sI, lane, i, (i+NQ-1)%NQ, C, S); ++off;
  }
}

// backward-order layer (mechanical transform of R7-verified layer_bwd)
__device__ __forceinline__ void layer_bwd2(F2* sR, F2* sI, unsigned lane,
                                           const float* P0, const float* P1,
                                           float dt0, float dt1, int& off) {
#pragma unroll
  for (int i = NQ-1; i >= 0; --i) {
    g_u2_w(sR, sI, lane, i, pack_u(P0, P1, dt0, dt1, off));
    off += 3;
  }
#pragma unroll
  for (int i = NQ-1; i >= 0; --i) {
    F2 C, S; pack_cs(P0, P1, off, C, S);
    crx2_w(sR, sI, lane, i, (i+NQ-1)%NQ, C, S); ++off;
  }
#pragma unroll
  for (int i = 0; i < NQ; ++i) {
    F2 C, S; pack_cs(P0, P1, off, C, S);
    crx2_w(sR, sI, lane, i, (i+1)%NQ, C, S); ++off;
  }
}

// RY-embedded |0..0> product state, both elems in F2 halves
__device__ __forceinline__ void init_state2e(F2* sR, F2* sI, unsigned lane,
                                             const float* ang0, const float* ang1) {
  float cw0[NQ], sw0[NQ], cw1[NQ], sw1[NQ];
#pragma unroll
  for (int w = 0; w < NQ; ++w) {
    __sincosf(ang0[w]*0.5f, &sw0[w], &cw0[w]);
    __sincosf(ang1[w]*0.5f, &sw1[w], &cw1[w]);
  }
  F2 L = mk2(1.0f, 1.0f);
#pragma unroll
  for (int q = 0; q < 6; ++q) {          // lane bit q <-> wire 5-q
    const int w = 5-q;
    L *= ((lane >> q) & 1u) ? mk2(sw0[w], sw1[w]) : mk2(cw0[w], cw1[w]);
  }
#pragma unroll
  for (int r = 0; r < 16; ++r) {
    F2 R = L;
#pragma unroll
    for (int p = 0; p < 4; ++p) {        // reg bit p <-> wire 9-p
      const int w = 9-p;
      R *= ((r >> p) & 1) ? mk2(sw0[w], sw1[w]) : mk2(cw0[w], cw1[w]);
    }
    sR[r] = R;
    sI[r] = mk2(0.0f, 0.0f);
  }
}

// ---------------- packed measurement (both elems at once) ----------------

template<int P>
__device__ __forceinline__ void meas2(const F2* sRe, const F2* sIm, unsigned lane,
                                      F2& X, F2& Y, F2& Z) {
  F2 cr = mk2(0,0), ci = mk2(0,0), z = mk2(0,0);
  if constexpr (P < 4) {
    constexpr int m = 1 << P;
#pragma unroll
    for (int r = 0; r < 16; ++r) if (!(r & m)) {
      const int r1 = r | m;
      F2 aR = sRe[r], aI = sIm[r], bR = sRe[r1], bI = sIm[r1];
      cr += aR*bR + aI*bI;
      ci += aR*bI - aI*bR;
      z  += (aR*aR + aI*aI) - (bR*bR + bI*bI);
    }
    cr = cr + cr; ci = ci + ci;          // *2
  } else {
    constexpr int lm = 1 << (P - 4);
    const bool hi = (lane & lm) != 0;
#pragma unroll
    for (int r = 0; r < 16; ++r) {
      F2 mR = sRe[r], mI = sIm[r];
      F2 oR = lshf2<lm>(mR), oI = lshf2<lm>(mI);
      F2 a0R = hi ? oR : mR, a0I = hi ? oI : mI;
      F2 a1R = hi ? mR : oR, a1I = hi ? mI : oI;
      cr += a0R*a1R + a0I*a1I;           // pair counted twice across lanes -> no *2
      ci += a0R*a1I - a0I*a1R;
      F2 p2 = mR*mR + mI*mI;
      z += hi ? -p2 : p2;
    }
  }
  X = cr; Y = ci; Z = z;
}

__device__ __forceinline__ F2 wred2(F2 v) {
  v += lshf2<1>(v);
  v += lshf2<2>(v);
  v += lshf2<4>(v);
  v += lshf2<8>(v);
  v += lshf2<16>(v);
  v += lshf2<32>(v);
  return v;
}

// ---------------- kernel: 1 block = 3 waves = 2 batch elems; one packed circuit per wave ----------------
// R13 structure unchanged; min-waves=3 caps VGPR at 85 (R13's live set is sR+sI=64 + ~16 temps,
// never two state arrays at once -> should fit without spill, unlike R12).
// Tripwire: WRITE_SIZE >> 1 MB means spill -> R7 (257us) is the roofline.

__global__ void __launch_bounds__(192, 3) qsim_kernel(
    const float* __restrict__ angles, const float* __restrict__ fwdP,
    const float* __restrict__ bwdP,   const float* __restrict__ diagP,
    const float* __restrict__ dts,
    const float* __restrict__ ar, const float* __restrict__ ai,
    const float* __restrict__ br, const float* __restrict__ bi,
    const float* __restrict__ gr, const float* __restrict__ gi,
    float* __restrict__ out)
{
  __shared__ F2 ldsR[2][16][64];   // weighted states of waves 1 (bwd), 2 (diag)
  __shared__ F2 ldsI[2][16][64];   // 32 KB total

  const int wave = threadIdx.x >> 6;
  const unsigned lane = threadIdx.x & 63u;
  const int b0 = blockIdx.x * 2;
  const int b1 = b0 + 1;

  const float* ang0 = angles + b0 * NQ;
  const float* ang1 = angles + b1 * NQ;
  const float dt0 = dts[b0], dt1 = dts[b1];

  const float arv = ar[0], aiv = ai[0], brv = br[0], biv = bi[0], grv = gr[0], giv = gi[0];
  const float nrm = sqrtf(arv*arv + aiv*aiv + brv*brv + biv*biv + grv*grv + giv*giv + 1e-9f);
  const float cAx = arv/nrm, cAy = aiv/nrm;
  const float cBx = brv/nrm, cBy = biv/nrm;
  const float cGx = grv/nrm, cGy = giv/nrm;

  F2 sR[16], sI[16];
  init_state2e(sR, sI, lane, ang0, ang1);

  if (wave == 0) {
    int off = 0;
    const float* P0 = fwdP + b0*NPRM;
    const float* P1 = fwdP + b1*NPRM;
#pragma unroll
    for (int l = 0; l < 2; ++l) layer_fwd2(sR, sI, lane, P0, P1, dt0, dt1, off);
  } else if (wave == 1) {
    int off = 0;
    const float* P0 = bwdP + b0*NPRM;
    const float* P1 = bwdP + b1*NPRM;
#pragma unroll
    for (int l = 0; l < 2; ++l) layer_bwd2(sR, sI, lane, P0, P1, dt0, dt1, off);
  } else {
    int off = 0;
    const float* P0 = diagP + b0*NPRM;
    const float* P1 = diagP + b1*NPRM;
#pragma unroll
    for (int l = 0; l < 2; ++l) layer_fwd2(sR, sI, lane, P0, P1, 1.0f, 1.0f, off);
  }

  if (wave != 0) {
    const float wx = (wave == 1) ? cBx : cGx;
    const float wy = (wave == 1) ? cBy : cGy;
#pragma unroll
    for (int r = 0; r < 16; ++r) {
      ldsR[wave-1][r][lane] = wx*sR[r] - wy*sI[r];
      ldsI[wave-1][r][lane] = wx*sI[r] + wy*sR[r];
    }
  }
  __syncthreads();
  if (wave != 0) return;

  // wave0: combine (cA * own fwd state + LDS states), normalize, measure
#pragma unroll
  for (int r = 0; r < 16; ++r) {
    F2 nR = cAx*sR[r] - cAy*sI[r] + ldsR[0][r][lane] + ldsR[1][r][lane];
    F2 nI = cAx*sI[r] + cAy*sR[r] + ldsI[0][r][lane] + ldsI[1][r][lane];
    sR[r] = nR; sI[r] = nI;
  }

  F2 n2 = mk2(0.0f, 0.0f);
#pragma unroll
  for (int r = 0; r < 16; ++r) n2 += sR[r]*sR[r] + sI[r]*sI[r];
  n2 = wred2(n2);
  const F2 inv = mk2(1.0f/(sqrtf(n2.x)+1e-9f), 1.0f/(sqrtf(n2.y)+1e-9f));
#pragma unroll
  for (int r = 0; r < 16; ++r) { sR[r] *= inv; sI[r] *= inv; }

  float* o0 = out + b0 * 30;
  float* o1 = out + b1 * 30;
#pragma unroll
  for (int w = 0; w < NQ; ++w) {
    F2 X, Y, Z;
    switch (w) {
      case 0: meas2<9>(sR, sI, lane, X, Y, Z); break;
      case 1: meas2<8>(sR, sI, lane, X, Y, Z); break;
      case 2: meas2<7>(sR, sI, lane, X, Y, Z); break;
      case 3: meas2<6>(sR, sI, lane, X, Y, Z); break;
      case 4: meas2<5>(sR, sI, lane, X, Y, Z); break;
      case 5: meas2<4>(sR, sI, lane, X, Y, Z); break;
      case 6: meas2<3>(sR, sI, lane, X, Y, Z); break;
      case 7: meas2<2>(sR, sI, lane, X, Y, Z); break;
      case 8: meas2<1>(sR, sI, lane, X, Y, Z); break;
      default: meas2<0>(sR, sI, lane, X, Y, Z); break;
    }
    X = wred2(X); Y = wred2(Y); Z = wred2(Z);
    if (lane == 0) {
      o0[w] = X.x; o0[10 + w] = Y.x; o0[20 + w] = Z.x;
      o1[w] = X.y; o1[10 + w] = Y.y; o1[20 + w] = Z.y;
    }
  }
}

extern "C" void kernel_launch(void* const* d_in, const int* in_sizes, int n_in,
                              void* d_out, int out_size, void* d_ws, size_t ws_size,
                              hipStream_t stream) {
  const float* angles = (const float*)d_in[0];
  const float* fwdP   = (const float*)d_in[1];
  const float* bwdP   = (const float*)d_in[2];
  const float* diagP  = (const float*)d_in[3];
  const float* dts    = (const float*)d_in[4];
  const float* ar     = (const float*)d_in[5];
  const float* ai     = (const float*)d_in[6];
  const float* br     = (const float*)d_in[7];
  const float* bi     = (const float*)d_in[8];
  const float* gr     = (const float*)d_in[9];
  const float* gi     = (const float*)d_in[10];
  float* out = (float*)d_out;

  // one block per 2 batch elements; 3 waves = {fwd, bwd, diag}, each packed over both elems
  qsim_kernel<<<NBATCH/2, 192, 0, stream>>>(
      angles, fwdP, bwdP, diagP, dts, ar, ai, br, bi, gr, gi, out);
}